// Round 1
// 137.730 us; speedup vs baseline: 1.0048x; 1.0048x over previous
//
#include <hip/hip_runtime.h>

// B=4, H=W=128, D=64, NH=2, hd=32, 9 taps. All inputs fp32; compute fp16 MFMA.
// R14 = R13 + attn_ff1 TLP rework: m=2 -> m=1 (16 px/wave), 1024-thr blocks
// (16 waves, 2 rows), grid stays 256 = 1 block/CU -> 4096 waves = 4 waves/SIMD
// (was 2). Full AK/BV/B1 LDS staging kept (157696 B, 1 block/CU); register
// queue 2-ahead (3 slots); lb(1024,4) caps VGPR at 128 for 4 waves/EU.
// prep / conv3x3 / conv3b unchanged from R13.

typedef _Float16 half8 __attribute__((ext_vector_type(8)));
typedef float f32x4 __attribute__((ext_vector_type(4)));

#define PLANE 524288  // 65536 pixels x 8 halves per plane

__device__ __forceinline__ f32x4 mfma16(half8 a, half8 b, f32x4 c) {
  return __builtin_amdgcn_mfma_f32_16x16x32_f16(a, b, c, 0, 0, 0);
}
__device__ __forceinline__ half8 ldfrag(const _Float16* p) { return *(const half8*)p; }
__device__ __forceinline__ half8 zfrag() { half8 z = {}; return z; }

__device__ __forceinline__ void gload_lds16(const _Float16* g, _Float16* l) {
  __builtin_amdgcn_global_load_lds(
      (const __attribute__((address_space(1))) void*)g,
      (__attribute__((address_space(3))) void*)l, 16, 0, 0);
}

// ---------------- prep: x -> fp16 octet planes + weight repack -------------
//   AQ  [mb4][kb2]      @ 0       AK  [t9][cb4][kb2]  @ 4096
//   BV  [t9][kb2][nb4]  @ 40960   B1  [kb2][nb4]      @ 77824
//   BF2 [t9][kb2][nb8]  @ 81920   BF3 [t9][kb4][nb4]  @ 155648  (229376 total)
__global__ __launch_bounds__(256) void prep(
    const float* __restrict__ x, const float* __restrict__ Kp,
    const float* __restrict__ Vp, const float* __restrict__ Qp,
    const float* __restrict__ W1, const float* __restrict__ F2,
    const float* __restrict__ F3, _Float16* __restrict__ xh,
    _Float16* __restrict__ out) {
  if (blockIdx.x < 2048) {
    const int t = threadIdx.x;
    const int px = blockIdx.x * 32 + (t >> 3);
    const int oct = t & 7;
    const float4* s = (const float4*)(x + (size_t)px * 64 + oct * 8);
    float4 a = s[0], b = s[1];
    half8 h = { (_Float16)a.x, (_Float16)a.y, (_Float16)a.z, (_Float16)a.w,
                (_Float16)b.x, (_Float16)b.y, (_Float16)b.z, (_Float16)b.w };
    *(half8*)(xh + (size_t)oct * PLANE + (size_t)px * 8) = h;
    return;
  }
  int e = (blockIdx.x - 2048) * 256 + threadIdx.x;  // 229376 total
  int j = e & 7, l = (e >> 3) & 63, f = e >> 9;
  int l15 = l & 15, q8 = (l >> 4) * 8;
  float v;
  if (f < 8)        { int mb = f >> 1, kb = f & 1;
                      v = Qp[(kb*32 + q8 + j) * 64 + mb*16 + l15]; }
  else if (f < 80)  { int g = f - 8, t = g >> 3, mb = (g >> 1) & 3, kb = g & 1;
                      v = Kp[(kb*32 + q8 + j) * 576 + t*64 + mb*16 + l15]; }
  else if (f < 152) { int g = f - 80, t = g >> 3, kb = (g >> 2) & 1, nb = g & 3;
                      v = Vp[(kb*32 + q8 + j) * 576 + t*64 + nb*16 + l15]; }
  else if (f < 160) { int g = f - 152, kb = g >> 2, nb = g & 3;
                      v = W1[(kb*32 + q8 + j) * 64 + nb*16 + l15]; }
  else if (f < 304) { int g = f - 160, t = g >> 4, kb = (g >> 3) & 1, nb = g & 7;
                      v = F2[(t*64 + kb*32 + q8 + j) * 128 + nb*16 + l15]; }
  else              { int g = f - 304, t = g >> 4, kb = (g >> 2) & 3, nb = g & 3;
                      v = F3[(t*128 + kb*32 + q8 + j) * 64 + nb*16 + l15]; }
  out[e] = (_Float16)v;
}

// ---------------- attention + ff1, one-pass online softmax -----------------
// 1024 thr = 16 waves; block = 2 rows; wave = 16 px (m=1). LDS (halves):
// AK[0,36864) BV[36864,73728) B1[73728,77824) dentab(f32) @77824.
// x-tap loads flow through a 3-slot register queue, 2 taps ahead.
__global__ __launch_bounds__(1024, 4) void attn_ff1(
    const _Float16* __restrict__ xh, const _Float16* __restrict__ wf,
    const float* __restrict__ f1b, _Float16* __restrict__ t1g) {
  extern __shared__ _Float16 smem[];
  const int lane = threadIdx.x & 63, wid = threadIdx.x >> 6;  // wid 0..15
  const int l15 = lane & 15, q8 = (lane >> 4) * 8;
  const int row = blockIdx.x * 2 + (wid >> 3);
  const int rw = wid & 7;
  const int p0 = row * 128 + rw * 16;
  const int h = row & 127;
  const int w0 = rw * 16;
  const int oct0 = lane >> 4;               // x0 plane; x1 plane = oct0+4
  float* dent = (float*)(smem + 77824) + wid * 32;

  // stage AK+BV+B1 (152 frags, 10/wave); in flight during qT + prologue
  {
    for (int i = 0; i < 10; ++i) {
      int f = wid * 10 + i;
      if (f < 152)
        gload_lds16(wf + 4096 + (size_t)f * 512 + lane * 8,
                    smem + (size_t)f * 512);
    }
  }

  // own-x fragments + q^T tiles
  half8 ax0, ax1;
  {
    const size_t px = (size_t)(p0 + l15);
    ax0 = ldfrag(xh + (size_t)oct0 * PLANE + px * 8);
    ax1 = ldfrag(xh + (size_t)(oct0 + 4) * PLANE + px * 8);
  }
  f32x4 qT[4];
#pragma unroll
  for (int cb = 0; cb < 4; ++cb) {
    half8 aq0 = ldfrag(wf + (cb * 2 + 0) * 512 + lane * 8);
    half8 aq1 = ldfrag(wf + (cb * 2 + 1) * 512 + lane * 8);
    f32x4 c = {};
    c = mfma16(aq0, ax0, c);
    c = mfma16(aq1, ax1, c);
    qT[cb] = c;
  }

  auto load_tap = [&](int t, half8& x0, half8& x1) {
    const int dh = t / 3 - 1, dw = t % 3 - 1;
    const bool rk = (unsigned)(h + dh) < 128u;
    const bool cv = rk && ((unsigned)(w0 + l15 + dw) < 128u);
    const size_t px = (size_t)(p0 + l15 + dh * 128 + dw);
    x0 = cv ? ldfrag(xh + (size_t)oct0 * PLANE + px * 8) : zfrag();
    x1 = cv ? ldfrag(xh + (size_t)(oct0 + 4) * PLANE + px * 8) : zfrag();
  };

  float den0 = 0.f, den1 = 0.f;
  auto score_tap = [&](int t, half8& x0, half8& x1, float& e0, float& e1) {
    const int dh = t / 3 - 1;
    const bool rowok = (unsigned)(h + dh) < 128u;
    half8 kf[8];
    if (rowok) {
#pragma unroll
      for (int f = 0; f < 8; ++f)
        kf[f] = ldfrag(smem + (t * 8 + f) * 512 + lane * 8);
    }
    float pa = 0.f, pb = 0.f;
    if (rowok) {
#pragma unroll
      for (int cb = 0; cb < 4; ++cb) {
        f32x4 c = {};
        c = mfma16(kf[cb * 2 + 0], x0, c);
        c = mfma16(kf[cb * 2 + 1], x1, c);
        float d = qT[cb].x * c.x + qT[cb].y * c.y
                + qT[cb].z * c.z + qT[cb].w * c.w;
        if (cb < 2) pa += d; else pb += d;
      }
      pa += __shfl_xor(pa, 16, 64); pa += __shfl_xor(pa, 32, 64);
      pb += __shfl_xor(pb, 16, 64); pb += __shfl_xor(pb, 32, 64);
    }
    e0 = __expf(pa * (1.f / 3.f));
    e1 = __expf(pb * (1.f / 3.f));
    den0 += e0; den1 += e1;
  };

  // 3-slot register queue, 2 taps in flight; prologue overlaps staging drain
  half8 q0[3], q1[3];
  load_tap(0, q0[0], q1[0]);
  load_tap(1, q0[1], q1[1]);

  __syncthreads();                          // staging complete

  float e0c, e1c;
  score_tap(0, q0[0], q1[0], e0c, e1c);

  const _Float16* BVl = smem + 36864;
  f32x4 at[4];
#pragma unroll
  for (int nb = 0; nb < 4; ++nb) at[nb] = f32x4{};

#pragma unroll
  for (int t = 0; t < 9; ++t) {
    if (t + 2 < 9) load_tap(t + 2, q0[(t + 2) % 3], q1[(t + 2) % 3]);
    const bool rowok = (unsigned)(h + (t / 3 - 1)) < 128u;
    if (rowok) {
      half8 vf[8];
#pragma unroll
      for (int f = 0; f < 8; ++f)
        vf[f] = ldfrag(BVl + (t * 8 + f) * 512 + lane * 8);
      _Float16 h0 = (_Float16)e0c, h1 = (_Float16)e1c;
      half8 b0 = {h0, h0, h0, h0, h0, h0, h0, h0};
      half8 b1 = {h1, h1, h1, h1, h1, h1, h1, h1};
      half8 s00 = q0[t % 3] * b0, s01 = q1[t % 3] * b0;
      half8 s10 = q0[t % 3] * b1, s11 = q1[t % 3] * b1;
#pragma unroll
      for (int nb = 0; nb < 2; ++nb) {
        at[nb]     = mfma16(s00, vf[0 * 4 + nb],     at[nb]);
        at[nb]     = mfma16(s01, vf[1 * 4 + nb],     at[nb]);
        at[nb + 2] = mfma16(s10, vf[0 * 4 + nb + 2], at[nb + 2]);
        at[nb + 2] = mfma16(s11, vf[1 * 4 + nb + 2], at[nb + 2]);
      }
    }
    if (t < 8) {
      float e0n, e1n;
      score_tap(t + 1, q0[(t + 1) % 3], q1[(t + 1) % 3], e0n, e1n);
      e0c = e0n; e1c = e1n;
    }
  }

  // per-pixel 1/den via per-wave LDS table
  dent[0 * 16 + l15] = den0;
  dent[1 * 16 + l15] = den1;
  f32x4 iv[2];
#pragma unroll
  for (int hd = 0; hd < 2; ++hd) {
    f32x4 dv = *(const f32x4*)(dent + hd * 16 + (lane >> 4) * 4);
    iv[hd] = f32x4{1.f / dv.x, 1.f / dv.y, 1.f / dv.z, 1.f / dv.w};
  }

  // -------- ff1: normalize + transpose -> GEMM -> CHUNKED plane store ------
  __syncthreads();                          // done reading AK/BV
  _Float16* myt = smem + wid * 1152;        // wave-private 16x72 tile
#pragma unroll
  for (int nb = 0; nb < 4; ++nb) {
    const int hd = nb >> 1;
#pragma unroll
    for (int r = 0; r < 4; ++r)
      myt[((lane >> 4) * 4 + r) * 72 + nb * 16 + l15] =
          (_Float16)(at[nb][r] * iv[hd][r]);
  }
  const _Float16* B1l = smem + 73728;
  const int pxl = lane >> 2;                // chunk readback: pixel 0..15
  const int co0 = lane & 3;                 // octs co0 and co0+4
  half8 aa0 = ldfrag(myt + l15 * 72 + q8);
  half8 aa1 = ldfrag(myt + l15 * 72 + 32 + q8);
#pragma unroll
  for (int nb = 0; nb < 4; ++nb) {
    f32x4 c = {};
    c = mfma16(aa0, ldfrag(B1l + (0 * 4 + nb) * 512 + lane * 8), c);
    c = mfma16(aa1, ldfrag(B1l + (1 * 4 + nb) * 512 + lane * 8), c);
    float bv = f1b[nb * 16 + l15];
#pragma unroll
    for (int r = 0; r < 4; ++r)             // overwrite tile (input dead)
      myt[((lane >> 4) * 4 + r) * 72 + nb * 16 + l15] =
          (_Float16)fmaxf(c[r] + bv, 0.f);
  }
  // readback 16B chunks, contiguous 16B stores (16 lanes/oct -> 256B runs)
  const size_t pxg = (size_t)(p0 + pxl);
  half8 h0 = ldfrag(myt + pxl * 72 + co0 * 8);
  half8 h1 = ldfrag(myt + pxl * 72 + (co0 + 4) * 8);
  *(half8*)(t1g + (size_t)co0 * PLANE + pxg * 8) = h0;
  *(half8*)(t1g + (size_t)(co0 + 4) * PLANE + pxg * 8) = h1;
}

// ---------------- conv2: 3x3, N-split, octet-plane I/O, DEPTH=3 (R12) ------
template <int KB, int NBL, int COUT, int DEPTH>
__global__ __launch_bounds__(512, 4) void conv3x3(
    const _Float16* __restrict__ in, const _Float16* __restrict__ wfrag,
    const float* __restrict__ bias, void* __restrict__ outp, int out_fp32) {
  extern __shared__ _Float16 smem[];
  constexpr int NS = DEPTH + 1;
  const int lane = threadIdx.x & 63, wid = threadIdx.x >> 6;
  const int l15 = lane & 15;
  const int nh = blockIdx.x & 1;
  const int pairIdx = blockIdx.x >> 1;
  const int row = pairIdx * 2 + (wid >> 2);
  const int rw = wid & 3;
  const int p0 = row * 128 + rw * 32;
  const int h = row & 127;
  const int w0 = rw * 32;
  const int NBF = COUT / 16;
  const int oct0 = lane >> 4;

  {
    for (int s = 0; s < 9; ++s) {
      int f = wid * 9 + s;
      int t = f >> 3, r = f & 7, kb = r / NBL, i = r % NBL;
      const _Float16* g = wfrag + (size_t)((t * KB + kb) * NBF + nh * NBL + i) * 512;
      gload_lds16(g + lane * 8, smem + f * 512);
    }
  }

  f32x4 acc[2][NBL];
#pragma unroll
  for (int m = 0; m < 2; ++m)
#pragma unroll
    for (int nb = 0; nb < NBL; ++nb) acc[m][nb] = f32x4{};

  auto load_conv = [&](int t, half8 (&dst)[2][KB]) {
    const int dh = t / 3 - 1, dw = t % 3 - 1;
    const bool rk = (unsigned)(h + dh) < 128u;
#pragma unroll
    for (int m = 0; m < 2; ++m) {
      const bool cv = rk && ((unsigned)(w0 + m * 16 + l15 + dw) < 128u);
      const size_t px = (size_t)(p0 + m * 16 + l15 + dh * 128 + dw);
#pragma unroll
      for (int kb = 0; kb < KB; ++kb)
        dst[m][kb] = cv ? ldfrag(in + (size_t)(kb * 4 + oct0) * PLANE + px * 8) : zfrag();
    }
  };

  half8 aq[NS][2][KB];
#pragma unroll
  for (int d = 0; d < DEPTH; ++d) load_conv(d, aq[d]);  // overlap staging

  __syncthreads();

#pragma unroll
  for (int t = 0; t < 9; ++t) {
    if (t + DEPTH < 9) load_conv(t + DEPTH, aq[(t + DEPTH) % NS]);
    const bool rowok = (unsigned)(h + (t / 3 - 1)) < 128u;
    if (rowok) {
#pragma unroll
      for (int nb = 0; nb < NBL; ++nb) {
#pragma unroll
        for (int kb = 0; kb < KB; ++kb) {
          half8 b = ldfrag(smem + (size_t)((t * KB + kb) * NBL + nb) * 512 + lane * 8);
          acc[0][nb] = mfma16(aq[t % NS][0][kb], b, acc[0][nb]);
          acc[1][nb] = mfma16(aq[t % NS][1][kb], b, acc[1][nb]);
        }
      }
    }
  }

  if (out_fp32) {
#pragma unroll
    for (int m = 0; m < 2; ++m)
#pragma unroll
      for (int nb = 0; nb < NBL; ++nb) {
        const int ch = nh * NBL * 16 + nb * 16 + l15;
        float bv = bias[ch];
#pragma unroll
        for (int r = 0; r < 4; ++r) {
          float v = fmaxf(acc[m][nb][r] + bv, 0.f);
          size_t px = (size_t)(p0 + m * 16 + (lane >> 4) * 4 + r);
          ((float*)outp)[px * COUT + ch] = v;
        }
      }
  } else {
    // fp16 plane output: chunked epilogue through wave-private LDS scratch
    __syncthreads();                        // weights dead for ALL waves now
    _Float16* T = smem + wid * 1152;        // wave-private 16x72 tile
    const int pxl = lane >> 2, co0 = lane & 3;
#pragma unroll
    for (int m = 0; m < 2; ++m) {
#pragma unroll
      for (int nb = 0; nb < NBL; ++nb) {
        const int chl = nb * 16 + l15;      // local ch within N-half (0..63)
        float bv = bias[nh * NBL * 16 + chl];
#pragma unroll
        for (int r = 0; r < 4; ++r)
          T[((lane >> 4) * 4 + r) * 72 + chl] =
              (_Float16)fmaxf(acc[m][nb][r] + bv, 0.f);
      }
      const size_t pxg = (size_t)(p0 + m * 16 + pxl);
      half8 h0 = ldfrag(T + pxl * 72 + co0 * 8);
      half8 h1 = ldfrag(T + pxl * 72 + (co0 + 4) * 8);
      *(half8*)((_Float16*)outp + (size_t)(nh * 8 + co0) * PLANE + pxg * 8) = h0;
      *(half8*)((_Float16*)outp + (size_t)(nh * 8 + co0 + 4) * PLANE + pxg * 8) = h1;
    }
  }
}

// ---------------- conv3: K-SPLIT two-pass (kb{0,1} then kb{2,3}), DEPTH=2 ---
// Block = 2 rows x 32 out-ch (N-half). Queue slot = 2m x 2kbl frags = 16 VGPR
// -> DEPTH=2 fits the lb(512,4) 128-VGPR cap (~95 est). Acc persists across
// passes; same total A/B traffic as the single-pass version.
__global__ __launch_bounds__(512, 4) void conv3b(
    const _Float16* __restrict__ in, const _Float16* __restrict__ wfrag,
    const float* __restrict__ bias, float* __restrict__ outp) {
  extern __shared__ _Float16 smem[];
  const int lane = threadIdx.x & 63, wid = threadIdx.x >> 6;
  const int l15 = lane & 15;
  const int nh = blockIdx.x & 1;
  const int pairIdx = blockIdx.x >> 1;
  const int row = pairIdx * 2 + (wid >> 2);
  const int rw = wid & 3;
  const int p0 = row * 128 + rw * 32;
  const int h = row & 127;
  const int w0 = rw * 32;
  const int oct0 = lane >> 4;
  const int KB = 4, NBL = 2, NBF = 4, COUT = 64;

  {  // stage this N-half's 72 frags (9/wave), layout f=(t*KB+kb)*NBL+nb
    for (int s = 0; s < 9; ++s) {
      int f = wid * 9 + s;
      int t = f >> 3, r = f & 7, kb = r / NBL, i = r % NBL;
      const _Float16* g = wfrag + (size_t)((t * KB + kb) * NBF + nh * NBL + i) * 512;
      gload_lds16(g + lane * 8, smem + f * 512);
    }
  }

  f32x4 acc[2][2];
#pragma unroll
  for (int m = 0; m < 2; ++m)
#pragma unroll
    for (int nb = 0; nb < 2; ++nb) acc[m][nb] = f32x4{};

#pragma unroll
  for (int p = 0; p < 2; ++p) {
    auto load_half = [&](int t, half8 (&dst)[2][2]) {
      const int dh = t / 3 - 1, dw = t % 3 - 1;
      const bool rk = (unsigned)(h + dh) < 128u;
#pragma unroll
      for (int m = 0; m < 2; ++m) {
        const bool cv = rk && ((unsigned)(w0 + m * 16 + l15 + dw) < 128u);
        const size_t px = (size_t)(p0 + m * 16 + l15 + dh * 128 + dw);
#pragma unroll
        for (int kbl = 0; kbl < 2; ++kbl)
          dst[m][kbl] = cv
              ? ldfrag(in + (size_t)((2 * p + kbl) * 4 + oct0) * PLANE + px * 8)
              : zfrag();
      }
    };

    half8 aq[3][2][2];
    load_half(0, aq[0]);
    load_half(1, aq[1]);
    if (p == 0) __syncthreads();            // staging complete (once)

#pragma unroll
    for (int t = 0; t < 9; ++t) {
      if (t + 2 < 9) load_half(t + 2, aq[(t + 2) % 3]);
      const bool rowok = (unsigned)(h + (t / 3 - 1)) < 128u;
      if (rowok) {
#pragma unroll
        for (int nb = 0; nb < 2; ++nb) {
#pragma unroll
          for (int kbl = 0; kbl < 2; ++kbl) {
            half8 b = ldfrag(smem +
                (size_t)((t * KB + 2 * p + kbl) * NBL + nb) * 512 + lane * 8);
            acc[0][nb] = mfma16(aq[t % 3][0][kbl], b, acc[0][nb]);
            acc[1][nb] = mfma16(aq[t % 3][1][kbl], b, acc[1][nb]);
          }
        }
      }
    }
  }

  // final output: pixel-major fp32, quad-contiguous 64B runs — direct store
#pragma unroll
  for (int m = 0; m < 2; ++m)
#pragma unroll
    for (int nb = 0; nb < 2; ++nb) {
      const int ch = nh * 32 + nb * 16 + l15;
      float bv = bias[ch];
#pragma unroll
      for (int r = 0; r < 4; ++r) {
        float v = fmaxf(acc[m][nb][r] + bv, 0.f);
        size_t px = (size_t)(p0 + m * 16 + (lane >> 4) * 4 + r);
        outp[px * COUT + ch] = v;
      }
    }
}

extern "C" void kernel_launch(void* const* d_in, const int* in_sizes, int n_in,
                              void* d_out, int out_size, void* d_ws, size_t ws_size,
                              hipStream_t stream) {
  (void)in_sizes; (void)n_in; (void)out_size; (void)ws_size;
  const float* x   = (const float*)d_in[0];
  const float* Kp  = (const float*)d_in[1];
  const float* Vp  = (const float*)d_in[2];
  const float* Qp  = (const float*)d_in[3];
  const float* f1w = (const float*)d_in[4];
  const float* f1b = (const float*)d_in[5];
  const float* f2w = (const float*)d_in[6];
  const float* f2b = (const float*)d_in[7];
  const float* f3w = (const float*)d_in[8];
  const float* f3b = (const float*)d_in[9];

  // ws (halves): xh 8 planes [0,4194304) | wf [4194304,4423680)
  // | t1 8 planes [4423680,8617984) | t2 16 planes [8617984,17006592)  ~34 MB
  _Float16* xh  = (_Float16*)d_ws;
  _Float16* wf  = xh + 4194304;
  _Float16* t1g = wf + 229376;
  _Float16* t2g = t1g + 4194304;
  float* outp = (float*)d_out;

  (void)hipFuncSetAttribute((const void*)attn_ff1,
      hipFuncAttributeMaxDynamicSharedMemorySize, 157696);
  (void)hipFuncSetAttribute((const void*)conv3x3<2, 4, 128, 3>,
      hipFuncAttributeMaxDynamicSharedMemorySize, 73728);
  (void)hipFuncSetAttribute((const void*)conv3b,
      hipFuncAttributeMaxDynamicSharedMemorySize, 73728);

  prep<<<2944, 256, 0, stream>>>(x, Kp, Vp, Qp, f1w, f2w, f3w, xh, wf);
  attn_ff1<<<256, 1024, 157696, stream>>>(xh, wf, f1b, t1g);
  conv3x3<2, 4, 128, 3><<<512, 512, 73728, stream>>>(t1g, wf + 81920, f2b, t2g, 0);
  conv3b<<<512, 512, 73728, stream>>>(t2g, wf + 155648, f3b, outp);
}

// Round 2
// 135.023 us; speedup vs baseline: 1.0249x; 1.0200x over previous
//
#include <hip/hip_runtime.h>

// B=4, H=W=128, D=64, NH=2, hd=32, 9 taps. All inputs fp32; compute fp16 MFMA.
// R15 = R14 + XCD-aware bijective block swizzle (T1) applied CONSISTENTLY:
// XCD k owns rows [64k, 64k+64) in prep(x part), attn_ff1, conv3x3, conv3b.
// Rationale: hardware round-robins consecutive blocks across 8 XCDs, so the
// 9-tap re-reads (xh/t1g/t2g, 75-151 MB of reads vs 4 MB per-XCD L2) were
// HBM-bound. Banded mapping makes the per-XCD tap working set ~1-2 MB (L2-fit)
// and aligns producer/consumer bands so intermediates stay warm in L2.
// Inner loops unchanged from R14.

typedef _Float16 half8 __attribute__((ext_vector_type(8)));
typedef float f32x4 __attribute__((ext_vector_type(4)));

#define PLANE 524288  // 65536 pixels x 8 halves per plane

__device__ __forceinline__ f32x4 mfma16(half8 a, half8 b, f32x4 c) {
  return __builtin_amdgcn_mfma_f32_16x16x32_f16(a, b, c, 0, 0, 0);
}
__device__ __forceinline__ half8 ldfrag(const _Float16* p) { return *(const half8*)p; }
__device__ __forceinline__ half8 zfrag() { half8 z = {}; return z; }

// bijective XCD swizzle: hardware assigns block n to XCD n%8; remap so XCD k
// processes logical blocks [k*chunk, (k+1)*chunk). Requires grid % 8 == 0.
__device__ __forceinline__ int xcd_swz(int n, int chunk) {
  return (n & 7) * chunk + (n >> 3);
}

__device__ __forceinline__ void gload_lds16(const _Float16* g, _Float16* l) {
  __builtin_amdgcn_global_load_lds(
      (const __attribute__((address_space(1))) void*)g,
      (__attribute__((address_space(3))) void*)l, 16, 0, 0);
}

// ---------------- prep: x -> fp16 octet planes + weight repack -------------
//   AQ  [mb4][kb2]      @ 0       AK  [t9][cb4][kb2]  @ 4096
//   BV  [t9][kb2][nb4]  @ 40960   B1  [kb2][nb4]      @ 77824
//   BF2 [t9][kb2][nb8]  @ 81920   BF3 [t9][kb4][nb4]  @ 155648  (229376 total)
__global__ __launch_bounds__(256) void prep(
    const float* __restrict__ x, const float* __restrict__ Kp,
    const float* __restrict__ Vp, const float* __restrict__ Qp,
    const float* __restrict__ W1, const float* __restrict__ F2,
    const float* __restrict__ F3, _Float16* __restrict__ xh,
    _Float16* __restrict__ out) {
  if (blockIdx.x < 2048) {
    const int b = xcd_swz(blockIdx.x, 256);  // XCD k: px band [k*8192,(k+1)*8192)
    const int t = threadIdx.x;
    const int px = b * 32 + (t >> 3);
    const int oct = t & 7;
    const float4* s = (const float4*)(x + (size_t)px * 64 + oct * 8);
    float4 a = s[0], b4 = s[1];
    half8 h = { (_Float16)a.x, (_Float16)a.y, (_Float16)a.z, (_Float16)a.w,
                (_Float16)b4.x, (_Float16)b4.y, (_Float16)b4.z, (_Float16)b4.w };
    *(half8*)(xh + (size_t)oct * PLANE + (size_t)px * 8) = h;
    return;
  }
  int e = (blockIdx.x - 2048) * 256 + threadIdx.x;  // 229376 total
  int j = e & 7, l = (e >> 3) & 63, f = e >> 9;
  int l15 = l & 15, q8 = (l >> 4) * 8;
  float v;
  if (f < 8)        { int mb = f >> 1, kb = f & 1;
                      v = Qp[(kb*32 + q8 + j) * 64 + mb*16 + l15]; }
  else if (f < 80)  { int g = f - 8, t = g >> 3, mb = (g >> 1) & 3, kb = g & 1;
                      v = Kp[(kb*32 + q8 + j) * 576 + t*64 + mb*16 + l15]; }
  else if (f < 152) { int g = f - 80, t = g >> 3, kb = (g >> 2) & 1, nb = g & 3;
                      v = Vp[(kb*32 + q8 + j) * 576 + t*64 + nb*16 + l15]; }
  else if (f < 160) { int g = f - 152, kb = g >> 2, nb = g & 3;
                      v = W1[(kb*32 + q8 + j) * 64 + nb*16 + l15]; }
  else if (f < 304) { int g = f - 160, t = g >> 4, kb = (g >> 3) & 1, nb = g & 7;
                      v = F2[(t*64 + kb*32 + q8 + j) * 128 + nb*16 + l15]; }
  else              { int g = f - 304, t = g >> 4, kb = (g >> 2) & 3, nb = g & 3;
                      v = F3[(t*128 + kb*32 + q8 + j) * 64 + nb*16 + l15]; }
  out[e] = (_Float16)v;
}

// ---------------- attention + ff1, one-pass online softmax -----------------
// 1024 thr = 16 waves; block = 2 rows; wave = 16 px (m=1). LDS (halves):
// AK[0,36864) BV[36864,73728) B1[73728,77824) dentab(f32) @77824.
// x-tap loads flow through a 3-slot register queue, 2 taps ahead.
__global__ __launch_bounds__(1024, 4) void attn_ff1(
    const _Float16* __restrict__ xh, const _Float16* __restrict__ wf,
    const float* __restrict__ f1b, _Float16* __restrict__ t1g) {
  extern __shared__ _Float16 smem[];
  const int lane = threadIdx.x & 63, wid = threadIdx.x >> 6;  // wid 0..15
  const int l15 = lane & 15, q8 = (lane >> 4) * 8;
  const int bid = xcd_swz(blockIdx.x, 32);  // XCD k: rows [64k, 64k+64)
  const int row = bid * 2 + (wid >> 3);
  const int rw = wid & 7;
  const int p0 = row * 128 + rw * 16;
  const int h = row & 127;
  const int w0 = rw * 16;
  const int oct0 = lane >> 4;               // x0 plane; x1 plane = oct0+4
  float* dent = (float*)(smem + 77824) + wid * 32;

  // stage AK+BV+B1 (152 frags, 10/wave); in flight during qT + prologue
  {
    for (int i = 0; i < 10; ++i) {
      int f = wid * 10 + i;
      if (f < 152)
        gload_lds16(wf + 4096 + (size_t)f * 512 + lane * 8,
                    smem + (size_t)f * 512);
    }
  }

  // own-x fragments + q^T tiles
  half8 ax0, ax1;
  {
    const size_t px = (size_t)(p0 + l15);
    ax0 = ldfrag(xh + (size_t)oct0 * PLANE + px * 8);
    ax1 = ldfrag(xh + (size_t)(oct0 + 4) * PLANE + px * 8);
  }
  f32x4 qT[4];
#pragma unroll
  for (int cb = 0; cb < 4; ++cb) {
    half8 aq0 = ldfrag(wf + (cb * 2 + 0) * 512 + lane * 8);
    half8 aq1 = ldfrag(wf + (cb * 2 + 1) * 512 + lane * 8);
    f32x4 c = {};
    c = mfma16(aq0, ax0, c);
    c = mfma16(aq1, ax1, c);
    qT[cb] = c;
  }

  auto load_tap = [&](int t, half8& x0, half8& x1) {
    const int dh = t / 3 - 1, dw = t % 3 - 1;
    const bool rk = (unsigned)(h + dh) < 128u;
    const bool cv = rk && ((unsigned)(w0 + l15 + dw) < 128u);
    const size_t px = (size_t)(p0 + l15 + dh * 128 + dw);
    x0 = cv ? ldfrag(xh + (size_t)oct0 * PLANE + px * 8) : zfrag();
    x1 = cv ? ldfrag(xh + (size_t)(oct0 + 4) * PLANE + px * 8) : zfrag();
  };

  float den0 = 0.f, den1 = 0.f;
  auto score_tap = [&](int t, half8& x0, half8& x1, float& e0, float& e1) {
    const int dh = t / 3 - 1;
    const bool rowok = (unsigned)(h + dh) < 128u;
    half8 kf[8];
    if (rowok) {
#pragma unroll
      for (int f = 0; f < 8; ++f)
        kf[f] = ldfrag(smem + (t * 8 + f) * 512 + lane * 8);
    }
    float pa = 0.f, pb = 0.f;
    if (rowok) {
#pragma unroll
      for (int cb = 0; cb < 4; ++cb) {
        f32x4 c = {};
        c = mfma16(kf[cb * 2 + 0], x0, c);
        c = mfma16(kf[cb * 2 + 1], x1, c);
        float d = qT[cb].x * c.x + qT[cb].y * c.y
                + qT[cb].z * c.z + qT[cb].w * c.w;
        if (cb < 2) pa += d; else pb += d;
      }
      pa += __shfl_xor(pa, 16, 64); pa += __shfl_xor(pa, 32, 64);
      pb += __shfl_xor(pb, 16, 64); pb += __shfl_xor(pb, 32, 64);
    }
    e0 = __expf(pa * (1.f / 3.f));
    e1 = __expf(pb * (1.f / 3.f));
    den0 += e0; den1 += e1;
  };

  // 3-slot register queue, 2 taps in flight; prologue overlaps staging drain
  half8 q0[3], q1[3];
  load_tap(0, q0[0], q1[0]);
  load_tap(1, q0[1], q1[1]);

  __syncthreads();                          // staging complete

  float e0c, e1c;
  score_tap(0, q0[0], q1[0], e0c, e1c);

  const _Float16* BVl = smem + 36864;
  f32x4 at[4];
#pragma unroll
  for (int nb = 0; nb < 4; ++nb) at[nb] = f32x4{};

#pragma unroll
  for (int t = 0; t < 9; ++t) {
    if (t + 2 < 9) load_tap(t + 2, q0[(t + 2) % 3], q1[(t + 2) % 3]);
    const bool rowok = (unsigned)(h + (t / 3 - 1)) < 128u;
    if (rowok) {
      half8 vf[8];
#pragma unroll
      for (int f = 0; f < 8; ++f)
        vf[f] = ldfrag(BVl + (t * 8 + f) * 512 + lane * 8);
      _Float16 h0 = (_Float16)e0c, h1 = (_Float16)e1c;
      half8 b0 = {h0, h0, h0, h0, h0, h0, h0, h0};
      half8 b1 = {h1, h1, h1, h1, h1, h1, h1, h1};
      half8 s00 = q0[t % 3] * b0, s01 = q1[t % 3] * b0;
      half8 s10 = q0[t % 3] * b1, s11 = q1[t % 3] * b1;
#pragma unroll
      for (int nb = 0; nb < 2; ++nb) {
        at[nb]     = mfma16(s00, vf[0 * 4 + nb],     at[nb]);
        at[nb]     = mfma16(s01, vf[1 * 4 + nb],     at[nb]);
        at[nb + 2] = mfma16(s10, vf[0 * 4 + nb + 2], at[nb + 2]);
        at[nb + 2] = mfma16(s11, vf[1 * 4 + nb + 2], at[nb + 2]);
      }
    }
    if (t < 8) {
      float e0n, e1n;
      score_tap(t + 1, q0[(t + 1) % 3], q1[(t + 1) % 3], e0n, e1n);
      e0c = e0n; e1c = e1n;
    }
  }

  // per-pixel 1/den via per-wave LDS table
  dent[0 * 16 + l15] = den0;
  dent[1 * 16 + l15] = den1;
  f32x4 iv[2];
#pragma unroll
  for (int hd = 0; hd < 2; ++hd) {
    f32x4 dv = *(const f32x4*)(dent + hd * 16 + (lane >> 4) * 4);
    iv[hd] = f32x4{1.f / dv.x, 1.f / dv.y, 1.f / dv.z, 1.f / dv.w};
  }

  // -------- ff1: normalize + transpose -> GEMM -> CHUNKED plane store ------
  __syncthreads();                          // done reading AK/BV
  _Float16* myt = smem + wid * 1152;        // wave-private 16x72 tile
#pragma unroll
  for (int nb = 0; nb < 4; ++nb) {
    const int hd = nb >> 1;
#pragma unroll
    for (int r = 0; r < 4; ++r)
      myt[((lane >> 4) * 4 + r) * 72 + nb * 16 + l15] =
          (_Float16)(at[nb][r] * iv[hd][r]);
  }
  const _Float16* B1l = smem + 73728;
  const int pxl = lane >> 2;                // chunk readback: pixel 0..15
  const int co0 = lane & 3;                 // octs co0 and co0+4
  half8 aa0 = ldfrag(myt + l15 * 72 + q8);
  half8 aa1 = ldfrag(myt + l15 * 72 + 32 + q8);
#pragma unroll
  for (int nb = 0; nb < 4; ++nb) {
    f32x4 c = {};
    c = mfma16(aa0, ldfrag(B1l + (0 * 4 + nb) * 512 + lane * 8), c);
    c = mfma16(aa1, ldfrag(B1l + (1 * 4 + nb) * 512 + lane * 8), c);
    float bv = f1b[nb * 16 + l15];
#pragma unroll
    for (int r = 0; r < 4; ++r)             // overwrite tile (input dead)
      myt[((lane >> 4) * 4 + r) * 72 + nb * 16 + l15] =
          (_Float16)fmaxf(c[r] + bv, 0.f);
  }
  // readback 16B chunks, contiguous 16B stores (16 lanes/oct -> 256B runs)
  const size_t pxg = (size_t)(p0 + pxl);
  half8 h0 = ldfrag(myt + pxl * 72 + co0 * 8);
  half8 h1 = ldfrag(myt + pxl * 72 + (co0 + 4) * 8);
  *(half8*)(t1g + (size_t)co0 * PLANE + pxg * 8) = h0;
  *(half8*)(t1g + (size_t)(co0 + 4) * PLANE + pxg * 8) = h1;
}

// ---------------- conv2: 3x3, N-split, octet-plane I/O, DEPTH=3 (R12) ------
template <int KB, int NBL, int COUT, int DEPTH>
__global__ __launch_bounds__(512, 4) void conv3x3(
    const _Float16* __restrict__ in, const _Float16* __restrict__ wfrag,
    const float* __restrict__ bias, void* __restrict__ outp, int out_fp32) {
  extern __shared__ _Float16 smem[];
  constexpr int NS = DEPTH + 1;
  const int lane = threadIdx.x & 63, wid = threadIdx.x >> 6;
  const int l15 = lane & 15;
  const int bid = xcd_swz(blockIdx.x, 64);  // XCD k: pairs [32k,32k+32), both nh
  const int nh = bid & 1;
  const int pairIdx = bid >> 1;
  const int row = pairIdx * 2 + (wid >> 2);
  const int rw = wid & 3;
  const int p0 = row * 128 + rw * 32;
  const int h = row & 127;
  const int w0 = rw * 32;
  const int NBF = COUT / 16;
  const int oct0 = lane >> 4;

  {
    for (int s = 0; s < 9; ++s) {
      int f = wid * 9 + s;
      int t = f >> 3, r = f & 7, kb = r / NBL, i = r % NBL;
      const _Float16* g = wfrag + (size_t)((t * KB + kb) * NBF + nh * NBL + i) * 512;
      gload_lds16(g + lane * 8, smem + f * 512);
    }
  }

  f32x4 acc[2][NBL];
#pragma unroll
  for (int m = 0; m < 2; ++m)
#pragma unroll
    for (int nb = 0; nb < NBL; ++nb) acc[m][nb] = f32x4{};

  auto load_conv = [&](int t, half8 (&dst)[2][KB]) {
    const int dh = t / 3 - 1, dw = t % 3 - 1;
    const bool rk = (unsigned)(h + dh) < 128u;
#pragma unroll
    for (int m = 0; m < 2; ++m) {
      const bool cv = rk && ((unsigned)(w0 + m * 16 + l15 + dw) < 128u);
      const size_t px = (size_t)(p0 + m * 16 + l15 + dh * 128 + dw);
#pragma unroll
      for (int kb = 0; kb < KB; ++kb)
        dst[m][kb] = cv ? ldfrag(in + (size_t)(kb * 4 + oct0) * PLANE + px * 8) : zfrag();
    }
  };

  half8 aq[NS][2][KB];
#pragma unroll
  for (int d = 0; d < DEPTH; ++d) load_conv(d, aq[d]);  // overlap staging

  __syncthreads();

#pragma unroll
  for (int t = 0; t < 9; ++t) {
    if (t + DEPTH < 9) load_conv(t + DEPTH, aq[(t + DEPTH) % NS]);
    const bool rowok = (unsigned)(h + (t / 3 - 1)) < 128u;
    if (rowok) {
#pragma unroll
      for (int nb = 0; nb < NBL; ++nb) {
#pragma unroll
        for (int kb = 0; kb < KB; ++kb) {
          half8 b = ldfrag(smem + (size_t)((t * KB + kb) * NBL + nb) * 512 + lane * 8);
          acc[0][nb] = mfma16(aq[t % NS][0][kb], b, acc[0][nb]);
          acc[1][nb] = mfma16(aq[t % NS][1][kb], b, acc[1][nb]);
        }
      }
    }
  }

  if (out_fp32) {
#pragma unroll
    for (int m = 0; m < 2; ++m)
#pragma unroll
      for (int nb = 0; nb < NBL; ++nb) {
        const int ch = nh * NBL * 16 + nb * 16 + l15;
        float bv = bias[ch];
#pragma unroll
        for (int r = 0; r < 4; ++r) {
          float v = fmaxf(acc[m][nb][r] + bv, 0.f);
          size_t px = (size_t)(p0 + m * 16 + (lane >> 4) * 4 + r);
          ((float*)outp)[px * COUT + ch] = v;
        }
      }
  } else {
    // fp16 plane output: chunked epilogue through wave-private LDS scratch
    __syncthreads();                        // weights dead for ALL waves now
    _Float16* T = smem + wid * 1152;        // wave-private 16x72 tile
    const int pxl = lane >> 2, co0 = lane & 3;
#pragma unroll
    for (int m = 0; m < 2; ++m) {
#pragma unroll
      for (int nb = 0; nb < NBL; ++nb) {
        const int chl = nb * 16 + l15;      // local ch within N-half (0..63)
        float bv = bias[nh * NBL * 16 + chl];
#pragma unroll
        for (int r = 0; r < 4; ++r)
          T[((lane >> 4) * 4 + r) * 72 + chl] =
              (_Float16)fmaxf(acc[m][nb][r] + bv, 0.f);
      }
      const size_t pxg = (size_t)(p0 + m * 16 + pxl);
      half8 h0 = ldfrag(T + pxl * 72 + co0 * 8);
      half8 h1 = ldfrag(T + pxl * 72 + (co0 + 4) * 8);
      *(half8*)((_Float16*)outp + (size_t)(nh * 8 + co0) * PLANE + pxg * 8) = h0;
      *(half8*)((_Float16*)outp + (size_t)(nh * 8 + co0 + 4) * PLANE + pxg * 8) = h1;
    }
  }
}

// ---------------- conv3: K-SPLIT two-pass (kb{0,1} then kb{2,3}), DEPTH=2 ---
// Block = 2 rows x 32 out-ch (N-half). Queue slot = 2m x 2kbl frags = 16 VGPR
// -> DEPTH=2 fits the lb(512,4) 128-VGPR cap (~95 est). Acc persists across
// passes; same total A/B traffic as the single-pass version.
__global__ __launch_bounds__(512, 4) void conv3b(
    const _Float16* __restrict__ in, const _Float16* __restrict__ wfrag,
    const float* __restrict__ bias, float* __restrict__ outp) {
  extern __shared__ _Float16 smem[];
  const int lane = threadIdx.x & 63, wid = threadIdx.x >> 6;
  const int l15 = lane & 15;
  const int bid = xcd_swz(blockIdx.x, 64);  // same banding as conv2 -> L2-warm
  const int nh = bid & 1;
  const int pairIdx = bid >> 1;
  const int row = pairIdx * 2 + (wid >> 2);
  const int rw = wid & 3;
  const int p0 = row * 128 + rw * 32;
  const int h = row & 127;
  const int w0 = rw * 32;
  const int oct0 = lane >> 4;
  const int KB = 4, NBL = 2, NBF = 4, COUT = 64;

  {  // stage this N-half's 72 frags (9/wave), layout f=(t*KB+kb)*NBL+nb
    for (int s = 0; s < 9; ++s) {
      int f = wid * 9 + s;
      int t = f >> 3, r = f & 7, kb = r / NBL, i = r % NBL;
      const _Float16* g = wfrag + (size_t)((t * KB + kb) * NBF + nh * NBL + i) * 512;
      gload_lds16(g + lane * 8, smem + f * 512);
    }
  }

  f32x4 acc[2][2];
#pragma unroll
  for (int m = 0; m < 2; ++m)
#pragma unroll
    for (int nb = 0; nb < 2; ++nb) acc[m][nb] = f32x4{};

#pragma unroll
  for (int p = 0; p < 2; ++p) {
    auto load_half = [&](int t, half8 (&dst)[2][2]) {
      const int dh = t / 3 - 1, dw = t % 3 - 1;
      const bool rk = (unsigned)(h + dh) < 128u;
#pragma unroll
      for (int m = 0; m < 2; ++m) {
        const bool cv = rk && ((unsigned)(w0 + m * 16 + l15 + dw) < 128u);
        const size_t px = (size_t)(p0 + m * 16 + l15 + dh * 128 + dw);
#pragma unroll
        for (int kbl = 0; kbl < 2; ++kbl)
          dst[m][kbl] = cv
              ? ldfrag(in + (size_t)((2 * p + kbl) * 4 + oct0) * PLANE + px * 8)
              : zfrag();
      }
    };

    half8 aq[3][2][2];
    load_half(0, aq[0]);
    load_half(1, aq[1]);
    if (p == 0) __syncthreads();            // staging complete (once)

#pragma unroll
    for (int t = 0; t < 9; ++t) {
      if (t + 2 < 9) load_half(t + 2, aq[(t + 2) % 3]);
      const bool rowok = (unsigned)(h + (t / 3 - 1)) < 128u;
      if (rowok) {
#pragma unroll
        for (int nb = 0; nb < 2; ++nb) {
#pragma unroll
          for (int kbl = 0; kbl < 2; ++kbl) {
            half8 b = ldfrag(smem +
                (size_t)((t * KB + 2 * p + kbl) * NBL + nb) * 512 + lane * 8);
            acc[0][nb] = mfma16(aq[t % 3][0][kbl], b, acc[0][nb]);
            acc[1][nb] = mfma16(aq[t % 3][1][kbl], b, acc[1][nb]);
          }
        }
      }
    }
  }

  // final output: pixel-major fp32, quad-contiguous 64B runs — direct store
#pragma unroll
  for (int m = 0; m < 2; ++m)
#pragma unroll
    for (int nb = 0; nb < 2; ++nb) {
      const int ch = nh * 32 + nb * 16 + l15;
      float bv = bias[ch];
#pragma unroll
      for (int r = 0; r < 4; ++r) {
        float v = fmaxf(acc[m][nb][r] + bv, 0.f);
        size_t px = (size_t)(p0 + m * 16 + (lane >> 4) * 4 + r);
        outp[px * COUT + ch] = v;
      }
    }
}

extern "C" void kernel_launch(void* const* d_in, const int* in_sizes, int n_in,
                              void* d_out, int out_size, void* d_ws, size_t ws_size,
                              hipStream_t stream) {
  (void)in_sizes; (void)n_in; (void)out_size; (void)ws_size;
  const float* x   = (const float*)d_in[0];
  const float* Kp  = (const float*)d_in[1];
  const float* Vp  = (const float*)d_in[2];
  const float* Qp  = (const float*)d_in[3];
  const float* f1w = (const float*)d_in[4];
  const float* f1b = (const float*)d_in[5];
  const float* f2w = (const float*)d_in[6];
  const float* f2b = (const float*)d_in[7];
  const float* f3w = (const float*)d_in[8];
  const float* f3b = (const float*)d_in[9];

  // ws (halves): xh 8 planes [0,4194304) | wf [4194304,4423680)
  // | t1 8 planes [4423680,8617984) | t2 16 planes [8617984,17006592)  ~34 MB
  _Float16* xh  = (_Float16*)d_ws;
  _Float16* wf  = xh + 4194304;
  _Float16* t1g = wf + 229376;
  _Float16* t2g = t1g + 4194304;
  float* outp = (float*)d_out;

  (void)hipFuncSetAttribute((const void*)attn_ff1,
      hipFuncAttributeMaxDynamicSharedMemorySize, 157696);
  (void)hipFuncSetAttribute((const void*)conv3x3<2, 4, 128, 3>,
      hipFuncAttributeMaxDynamicSharedMemorySize, 73728);
  (void)hipFuncSetAttribute((const void*)conv3b,
      hipFuncAttributeMaxDynamicSharedMemorySize, 73728);

  prep<<<2944, 256, 0, stream>>>(x, Kp, Vp, Qp, f1w, f2w, f3w, xh, wf);
  attn_ff1<<<256, 1024, 157696, stream>>>(xh, wf, f1b, t1g);
  conv3x3<2, 4, 128, 3><<<512, 512, 73728, stream>>>(t1g, wf + 81920, f2b, t2g, 0);
  conv3b<<<512, 512, 73728, stream>>>(t2g, wf + 155648, f3b, outp);
}